// Round 7
// baseline (5711.414 us; speedup 1.0000x reference)
//
#include <hip/hip_runtime.h>
#include <cstdint>
#include <cstddef>

#define TT 1000
#define NB 64000  // B*T

// ---------------------------------------------------------------------------
// NUMERICS CONTRACT (r1/r5 verified absmax 0.0): each z[n,o] is ONE
// ascending-k fp32 fmaf chain. Do not reorder, split, or tree-reduce.
// ---------------------------------------------------------------------------

// async global->LDS DMA: 16B/lane; LDS dest = wave-uniform base + lane*16
__device__ __forceinline__ void dma16(const float* g, float* l) {
  __builtin_amdgcn_global_load_lds(
      (const __attribute__((address_space(1))) unsigned int*)g,
      (__attribute__((address_space(3))) unsigned int*)l, 16, 0, 0);
}

// ---------------------------------------------------------------------------
// gemm_areg: Z[n,o] = sum_k Wt[k][o] * S[n][k]
// S: [N,K] u8 (0/1); Wt: [K,Wld] f32 pre-transposed; Z: [N,Zld] f32.
// 128n x 128o tile, BK=16, 256 thr, 8x8/thread.
// A lives in REGISTERS as u8 (uint4 = 16 k per row), converted per k-step
// via the (dw>>sh)&0xff idiom -> v_cvt_f32_ubyte. Only B goes through LDS
// (2x ds_read_b128/k-step): LDS demand 96 cyc/CU < VALU 148 -> VALU-bound
// (r1 was LDS-BW-bound at 85 B/cyc/CU per m134; that was the 104us wall).
// B double-buffered via zero-VGPR global_load_lds, one barrier per k-tile.
// ---------------------------------------------------------------------------
__global__ __launch_bounds__(256, 4) void gemm_areg(
    const uint8_t* __restrict__ S, const float* __restrict__ Wt,
    float* __restrict__ Z, int K, int Wld, int Zld, int Ostore) {
  __shared__ __align__(16) float Bs[2][2048];
  const int t = threadIdx.x;
  const int lane = t & 63;
  const int wave = t >> 6;
  const int bn = blockIdx.x * 128;
  const int bo = blockIdx.y * 128;
  const int tx4 = (t & 15) * 4;
  const int ty4 = ((t >> 4) & 15) * 4;

  // B DMA geometry: flat 2048-float tile; wave covers 2x 1KB segments
  const int f0 = wave * 64 + lane;  // lane covers floats [f0*4, f0*4+4)
  const int bk0 = f0 >> 5;          // k-row 0..7 (second DMA: +8)
  const int bc0 = (f0 & 31) * 4;
  const float* wrow0 = Wt + (size_t)bk0 * Wld + bo + bc0;
  const float* wrow1 = wrow0 + (size_t)8 * Wld;

  // A rows for this thread: bn+ty4+j and bn+64+ty4+j (j<4)
  const uint8_t* arow0 = S + (size_t)(bn + ty4) * K;
  const uint8_t* arow1 = S + (size_t)(bn + 64 + ty4) * K;

  float acc[8][8];
#pragma unroll
  for (int j = 0; j < 8; j++)
#pragma unroll
    for (int i = 0; i < 8; i++) acc[j][i] = 0.f;

  unsigned int A[8][4];  // 8 rows x 16 k (u8 packed)

  // prologue: stage tile 0
  dma16(wrow0, &Bs[0][wave * 256]);
  dma16(wrow1, &Bs[0][1024 + wave * 256]);
#pragma unroll
  for (int j = 0; j < 4; j++) {
    *(uint4*)A[j] = *(const uint4*)(arow0 + (size_t)j * K);
    *(uint4*)A[4 + j] = *(const uint4*)(arow1 + (size_t)j * K);
  }
  __syncthreads();

  const int nt = K >> 4;
  for (int tile = 0; tile < nt; tile++) {
    const int cur = tile & 1;
    const bool more = (tile + 1 < nt);
    if (more) {  // async B prefetch for next tile (lands during compute)
      const float* wn = wrow0 + (size_t)(tile + 1) * 16 * Wld;
      dma16(wn, &Bs[cur ^ 1][wave * 256]);
      dma16(wn + (size_t)8 * Wld, &Bs[cur ^ 1][1024 + wave * 256]);
    }
    const float* bp = Bs[cur];
#pragma unroll
    for (int kk = 0; kk < 16; kk++) {
      const int d = kk >> 2, sh = (kk & 3) * 8;
      float av[8];
#pragma unroll
      for (int j = 0; j < 8; j++)
        av[j] = (float)((A[j][d] >> sh) & 0xffu);  // v_cvt_f32_ubyte
      float4 b0 = *(const float4*)&bp[kk * 128 + tx4];
      float4 b1 = *(const float4*)&bp[kk * 128 + 64 + tx4];
      float bv[8] = {b0.x, b0.y, b0.z, b0.w, b1.x, b1.y, b1.z, b1.w};
#pragma unroll
      for (int j = 0; j < 8; j++)
#pragma unroll
        for (int i = 0; i < 8; i++)
          acc[j][i] = fmaf(av[j], bv[i], acc[j][i]);
    }
    if (more) {  // A for next tile, issued after last use (WAR keeps order)
      const size_t ko = (size_t)(tile + 1) * 16;
#pragma unroll
      for (int j = 0; j < 4; j++) {
        *(uint4*)A[j] = *(const uint4*)(arow0 + (size_t)j * K + ko);
        *(uint4*)A[4 + j] = *(const uint4*)(arow1 + (size_t)j * K + ko);
      }
    }
    __syncthreads();  // drains DMA + A loads, then barrier
  }

  // store (N multiple of 128; o guarded vs Ostore)
#pragma unroll
  for (int jp = 0; jp < 2; jp++) {
#pragma unroll
    for (int j = 0; j < 4; j++) {
      int n = bn + jp * 64 + ty4 + j;
#pragma unroll
      for (int ip = 0; ip < 2; ip++) {
        int o0 = bo + ip * 64 + tx4;
        const float* a = &acc[jp * 4 + j][ip * 4];
        float* zp = Z + (size_t)n * Zld + o0;
        if (o0 + 3 < Ostore) {
          *(float4*)zp = make_float4(a[0], a[1], a[2], a[3]);
        } else {
#pragma unroll
          for (int q = 0; q < 4; q++)
            if (o0 + q < Ostore) zp[q] = a[q];
        }
      }
    }
  }
}

// ---------------------------------------------------------------------------
// CUBA LIF recurrence: depth-4 x U=25 load pipeline. Exact per-step fp32
// mul/add chain. u8 spike out [n][k] (next layer's A rows).
// ---------------------------------------------------------------------------
template <bool FINAL>
__global__ __launch_bounds__(64) void cuba_kernel(
    const float* __restrict__ Z, uint8_t* __restrict__ Sout,
    float* __restrict__ Fout, unsigned int* __restrict__ cnt, int O,
    int total) {
  int gid = blockIdx.x * 64 + threadIdx.x;
  unsigned int c = 0;
  if (gid < total) {
    int b = gid / O;
    int o = gid - b * O;
    const float* zp = Z + (size_t)b * TT * O + o;
    uint8_t* sp = Sout + (size_t)b * TT * O + o;
    float* fp = Fout + ((size_t)b * O + o) * TT;
    float cur = 0.f, volt = 0.f;
    constexpr int U = 25;
    float z0[U], z1[U], z2[U], z3[U];

#define LOADB(buf, tbase)                         \
  _Pragma("unroll") for (int u = 0; u < U; u++) { \
    buf[u] = zp[(size_t)((tbase) + u) * O];       \
  }
#define COMPB(buf, tbase)                                      \
  _Pragma("unroll") for (int u = 0; u < U; u++) {              \
    cur = __fadd_rn(__fmul_rn(0.75f, cur), buf[u]);            \
    volt = __fadd_rn(__fmul_rn(0.97f, volt), cur);             \
    bool fire = volt >= 1.25f;                                 \
    volt = fire ? 0.f : volt;                                  \
    c += fire ? 1u : 0u;                                       \
    if (FINAL)                                                 \
      fp[(tbase) + u] = fire ? 1.f : 0.f;                      \
    else                                                       \
      sp[(size_t)((tbase) + u) * O] = (uint8_t)(fire ? 1 : 0); \
  }

    LOADB(z0, 0)
    LOADB(z1, U)
    LOADB(z2, 2 * U)
    for (int i = 0; i < 10; i++) {
      const int base = i * 4 * U;
      LOADB(z3, base + 3 * U)
      COMPB(z0, base)
      if (i < 9) LOADB(z0, base + 4 * U)
      COMPB(z1, base + U)
      if (i < 9) LOADB(z1, base + 5 * U)
      COMPB(z2, base + 2 * U)
      if (i < 9) LOADB(z2, base + 6 * U)
      COMPB(z3, base + 3 * U)
    }
#undef LOADB
#undef COMPB
  }
#pragma unroll
  for (int off = 32; off; off >>= 1) c += __shfl_down(c, off, 64);
  if ((threadIdx.x & 63) == 0) atomicAdd(cnt, c);
}

// ---------------------------------------------------------------------------
// Input: [B,20,T] f32 -> [B*T, 32] u8 (K zero-padded)
// ---------------------------------------------------------------------------
__global__ __launch_bounds__(256) void prep_input(const float* __restrict__ X,
                                                  uint8_t* __restrict__ Sp) {
  int gid = blockIdx.x * 256 + threadIdx.x;
  if (gid >= NB) return;
  int b = gid / TT, tt = gid - b * TT;
  unsigned int w[8];
#pragma unroll
  for (int i = 0; i < 8; i++) w[i] = 0u;
#pragma unroll
  for (int c = 0; c < 20; c++) {
    float v = X[((size_t)b * 20 + c) * TT + tt];
    unsigned int bit = (v != 0.f) ? 1u : 0u;
    w[c >> 2] |= bit << ((c & 3) * 8);
  }
  uint4* dst = (uint4*)(Sp + (size_t)gid * 32);
  dst[0] = make_uint4(w[0], w[1], w[2], w[3]);
  dst[1] = make_uint4(w[4], w[5], w[6], w[7]);
}

// W [O,K] -> Wt [Kpad,Opad] transposed + zero-padded (value-exact copy)
__global__ __launch_bounds__(256) void prep_w(const float* __restrict__ W,
                                              float* __restrict__ Wt, int O,
                                              int K, int Kpad, int Opad) {
  int i = blockIdx.x * 256 + threadIdx.x;
  if (i >= Kpad * Opad) return;
  int k = i / Opad, o = i - k * Opad;
  Wt[i] = (k < K && o < O) ? W[(size_t)o * K + k] : 0.f;
}

__global__ void finalize_counts(const unsigned int* __restrict__ cnt,
                                float* __restrict__ out) {
  int i = threadIdx.x;
  if (i < 4) {
    const float denom[4] = {16384000.f, 16384000.f, 16384000.f, 2240000.f};
    out[i] = (float)cnt[i] / denom[i];
  }
}

// ---------------------------------------------------------------------------
extern "C" void kernel_launch(void* const* d_in, const int* in_sizes, int n_in,
                              void* d_out, int out_size, void* d_ws,
                              size_t ws_size, hipStream_t stream) {
  const float* X = (const float*)d_in[0];
  const float* W1 = (const float*)d_in[1];
  const float* W2 = (const float*)d_in[2];
  const float* W3 = (const float*)d_in[3];
  const float* W4 = (const float*)d_in[4];
  float* out = (float*)d_out;

  char* ws = (char*)d_ws;
  unsigned int* cnt = (unsigned int*)ws;             // 256 B
  float* Z = (float*)(ws + 256);                     // 65,536,000
  uint8_t* Sa = (uint8_t*)(ws + 256 + 65536000ull);  // 16,384,000
  uint8_t* Sb = Sa + 16384000ull;                    // 16,384,000
  uint8_t* Sin = Sb + 16384000ull;                   // 2,048,000
  float* Wt1 = (float*)(Sin + 2048000ull);           // 32*256*4
  float* Wt2 = Wt1 + 32 * 256;                       // 256*256*4
  float* Wt3 = Wt2 + 256 * 256;                      // 256*256*4
  float* Wt4 = Wt3 + 256 * 256;                      // 256*128*4

  hipMemsetAsync(cnt, 0, 16, stream);
  prep_w<<<(32 * 256 + 255) / 256, 256, 0, stream>>>(W1, Wt1, 256, 20, 32, 256);
  prep_w<<<(256 * 256) / 256, 256, 0, stream>>>(W2, Wt2, 256, 256, 256, 256);
  prep_w<<<(256 * 256) / 256, 256, 0, stream>>>(W3, Wt3, 256, 256, 256, 256);
  prep_w<<<(256 * 128) / 256, 256, 0, stream>>>(W4, Wt4, 35, 256, 256, 128);
  prep_input<<<(NB + 255) / 256, 256, 0, stream>>>(X, Sin);

  dim3 gBig(500, 2);  // 128-row tiles, O=256
  dim3 gOut(500, 1);  // O<=128 (layer 4)

  gemm_areg<<<gBig, 256, 0, stream>>>(Sin, Wt1, Z, 32, 256, 256, 256);
  cuba_kernel<false><<<256, 64, 0, stream>>>(Z, Sa, nullptr, cnt + 0, 256,
                                             16384);
  gemm_areg<<<gBig, 256, 0, stream>>>(Sa, Wt2, Z, 256, 256, 256, 256);
  cuba_kernel<false><<<256, 64, 0, stream>>>(Z, Sb, nullptr, cnt + 1, 256,
                                             16384);
  gemm_areg<<<gBig, 256, 0, stream>>>(Sb, Wt3, Z, 256, 256, 256, 256);
  cuba_kernel<false><<<256, 64, 0, stream>>>(Z, Sa, nullptr, cnt + 2, 256,
                                             16384);
  gemm_areg<<<gOut, 256, 0, stream>>>(Sa, Wt4, Z, 256, 128, 35, 35);
  cuba_kernel<true><<<35, 64, 0, stream>>>(Z, nullptr, out, cnt + 3, 35, 2240);
  finalize_counts<<<1, 64, 0, stream>>>(cnt, out + 2240000);
}

// Round 8
// 502.759 us; speedup vs baseline: 11.3601x; 11.3601x over previous
//
#include <hip/hip_runtime.h>
#include <cstdint>
#include <cstddef>

#define TT 1000
#define NB 64000  // B*T

// ---------------------------------------------------------------------------
// NUMERICS CONTRACT (r1/r5/r6 verified absmax 0.0): each z[n,o] is ONE
// ascending-k fp32 fmaf chain. Do not reorder, split, or tree-reduce.
// ---------------------------------------------------------------------------

// ---------------------------------------------------------------------------
// gemm_u8: Z[n,o] = sum_k Wt[k][o] * S[n][k]
// S: [N,K] u8 (0/1); Wt: [K,Wld] f32 pre-transposed; Z: [N,Zld] f32.
// 128n x 128o tile, BK=16, 256 thr, 8x8/thread, 2-barrier loop (r1-proven).
// A tile lives in LDS as PACKED U8 (u32[4][128] = 2 KB): per 4-k chunk two
// ds_read_b128 pull 8 rows' dwords into uint4 named fields (VGPR-safe),
// bytes converted with the (dw>>8j)&0xff -> v_cvt_f32_ubyte idiom.
// LDS traffic/kk/thread: 32 B (B) + 8 B (A) = 40 vs r1's 64 -> VALU-bound.
// ---------------------------------------------------------------------------
__global__ __launch_bounds__(256) void gemm_u8(const uint8_t* __restrict__ S,
                                               const float* __restrict__ Wt,
                                               float* __restrict__ Z, int K,
                                               int Wld, int Zld, int Ostore) {
  __shared__ unsigned int AsU[4][128];       // [kq][row] packed 4-k bytes
  __shared__ __align__(16) float Bs[16][128];
  const int t = threadIdx.x;
  const int bn = blockIdx.x * 128;
  const int bo = blockIdx.y * 128;
  const int tx4 = (t & 15) * 4;
  const int ty4 = ((t >> 4) & 15) * 4;
  const int bf0 = t * 4, bf1 = 1024 + t * 4;
  const int bk0 = bf0 >> 7, bc0 = bf0 & 127;
  const int bk1 = bf1 >> 7, bc1 = bf1 & 127;

  float acc[8][8];
#pragma unroll
  for (int j = 0; j < 8; j++)
#pragma unroll
    for (int i = 0; i < 8; i++) acc[j][i] = 0.f;

  for (int k0 = 0; k0 < K; k0 += 16) {
    // stage A: threads 0-127, one row each (16 k as uint4); conflict-free
    if (t < 128) {
      uint4 v = *(const uint4*)(S + (size_t)(bn + t) * K + k0);
      AsU[0][t] = v.x;
      AsU[1][t] = v.y;
      AsU[2][t] = v.z;
      AsU[3][t] = v.w;
    }
    // stage B: flat coalesced float4 copy, conflict-free
    *(float4*)&Bs[bk0][bc0] =
        *(const float4*)(Wt + (size_t)(k0 + bk0) * Wld + bo + bc0);
    *(float4*)&Bs[bk1][bc1] =
        *(const float4*)(Wt + (size_t)(k0 + bk1) * Wld + bo + bc1);
    __syncthreads();

#pragma unroll
    for (int kq = 0; kq < 4; kq++) {
      // 8 rows' packed dwords for this 4-k chunk (broadcast reads)
      uint4 a0 = *(const uint4*)&AsU[kq][ty4];
      uint4 a1 = *(const uint4*)&AsU[kq][64 + ty4];
#pragma unroll
      for (int k2 = 0; k2 < 4; k2++) {
        const int kk = kq * 4 + k2;
        const int sh = k2 * 8;
        float av[8];
        av[0] = (float)((a0.x >> sh) & 0xffu);
        av[1] = (float)((a0.y >> sh) & 0xffu);
        av[2] = (float)((a0.z >> sh) & 0xffu);
        av[3] = (float)((a0.w >> sh) & 0xffu);
        av[4] = (float)((a1.x >> sh) & 0xffu);
        av[5] = (float)((a1.y >> sh) & 0xffu);
        av[6] = (float)((a1.z >> sh) & 0xffu);
        av[7] = (float)((a1.w >> sh) & 0xffu);
        float4 b0 = *(const float4*)&Bs[kk][tx4];
        float4 b1 = *(const float4*)&Bs[kk][64 + tx4];
        float bv[8] = {b0.x, b0.y, b0.z, b0.w, b1.x, b1.y, b1.z, b1.w};
#pragma unroll
        for (int j = 0; j < 8; j++)
#pragma unroll
          for (int i = 0; i < 8; i++)
            acc[j][i] = fmaf(av[j], bv[i], acc[j][i]);
      }
    }
    __syncthreads();
  }

  // store (N multiple of 128; o guarded vs Ostore)
#pragma unroll
  for (int jp = 0; jp < 2; jp++) {
#pragma unroll
    for (int j = 0; j < 4; j++) {
      int n = bn + jp * 64 + ty4 + j;
#pragma unroll
      for (int ip = 0; ip < 2; ip++) {
        int o0 = bo + ip * 64 + tx4;
        const float* a = &acc[jp * 4 + j][ip * 4];
        float* zp = Z + (size_t)n * Zld + o0;
        if (o0 + 3 < Ostore) {
          *(float4*)zp = make_float4(a[0], a[1], a[2], a[3]);
        } else {
#pragma unroll
          for (int q = 0; q < 4; q++)
            if (o0 + q < Ostore) zp[q] = a[q];
        }
      }
    }
  }
}

// ---------------------------------------------------------------------------
// CUBA LIF recurrence: depth-4 x U=25 load pipeline. Exact per-step fp32
// mul/add chain. u8 spike out [n][k] (next layer's A rows).
// ---------------------------------------------------------------------------
template <bool FINAL>
__global__ __launch_bounds__(64) void cuba_kernel(
    const float* __restrict__ Z, uint8_t* __restrict__ Sout,
    float* __restrict__ Fout, unsigned int* __restrict__ cnt, int O,
    int total) {
  int gid = blockIdx.x * 64 + threadIdx.x;
  unsigned int c = 0;
  if (gid < total) {
    int b = gid / O;
    int o = gid - b * O;
    const float* zp = Z + (size_t)b * TT * O + o;
    uint8_t* sp = Sout + (size_t)b * TT * O + o;
    float* fp = Fout + ((size_t)b * O + o) * TT;
    float cur = 0.f, volt = 0.f;
    constexpr int U = 25;
    float z0[U], z1[U], z2[U], z3[U];

#define LOADB(buf, tbase)                         \
  _Pragma("unroll") for (int u = 0; u < U; u++) { \
    buf[u] = zp[(size_t)((tbase) + u) * O];       \
  }
#define COMPB(buf, tbase)                                      \
  _Pragma("unroll") for (int u = 0; u < U; u++) {              \
    cur = __fadd_rn(__fmul_rn(0.75f, cur), buf[u]);            \
    volt = __fadd_rn(__fmul_rn(0.97f, volt), cur);             \
    bool fire = volt >= 1.25f;                                 \
    volt = fire ? 0.f : volt;                                  \
    c += fire ? 1u : 0u;                                       \
    if (FINAL)                                                 \
      fp[(tbase) + u] = fire ? 1.f : 0.f;                      \
    else                                                       \
      sp[(size_t)((tbase) + u) * O] = (uint8_t)(fire ? 1 : 0); \
  }

    LOADB(z0, 0)
    LOADB(z1, U)
    LOADB(z2, 2 * U)
    for (int i = 0; i < 10; i++) {
      const int base = i * 4 * U;
      LOADB(z3, base + 3 * U)
      COMPB(z0, base)
      if (i < 9) LOADB(z0, base + 4 * U)
      COMPB(z1, base + U)
      if (i < 9) LOADB(z1, base + 5 * U)
      COMPB(z2, base + 2 * U)
      if (i < 9) LOADB(z2, base + 6 * U)
      COMPB(z3, base + 3 * U)
    }
#undef LOADB
#undef COMPB
  }
#pragma unroll
  for (int off = 32; off; off >>= 1) c += __shfl_down(c, off, 64);
  if ((threadIdx.x & 63) == 0) atomicAdd(cnt, c);
}

// ---------------------------------------------------------------------------
// Input: [B,20,T] f32 -> [B*T, 32] u8 (K zero-padded)
// ---------------------------------------------------------------------------
__global__ __launch_bounds__(256) void prep_input(const float* __restrict__ X,
                                                  uint8_t* __restrict__ Sp) {
  int gid = blockIdx.x * 256 + threadIdx.x;
  if (gid >= NB) return;
  int b = gid / TT, tt = gid - b * TT;
  unsigned int w[8];
#pragma unroll
  for (int i = 0; i < 8; i++) w[i] = 0u;
#pragma unroll
  for (int c = 0; c < 20; c++) {
    float v = X[((size_t)b * 20 + c) * TT + tt];
    unsigned int bit = (v != 0.f) ? 1u : 0u;
    w[c >> 2] |= bit << ((c & 3) * 8);
  }
  uint4* dst = (uint4*)(Sp + (size_t)gid * 32);
  dst[0] = make_uint4(w[0], w[1], w[2], w[3]);
  dst[1] = make_uint4(w[4], w[5], w[6], w[7]);
}

// W [O,K] -> Wt [Kpad,Opad] transposed + zero-padded (value-exact copy)
__global__ __launch_bounds__(256) void prep_w(const float* __restrict__ W,
                                              float* __restrict__ Wt, int O,
                                              int K, int Kpad, int Opad) {
  int i = blockIdx.x * 256 + threadIdx.x;
  if (i >= Kpad * Opad) return;
  int k = i / Opad, o = i - k * Opad;
  Wt[i] = (k < K && o < O) ? W[(size_t)o * K + k] : 0.f;
}

__global__ void finalize_counts(const unsigned int* __restrict__ cnt,
                                float* __restrict__ out) {
  int i = threadIdx.x;
  if (i < 4) {
    const float denom[4] = {16384000.f, 16384000.f, 16384000.f, 2240000.f};
    out[i] = (float)cnt[i] / denom[i];
  }
}

// ---------------------------------------------------------------------------
extern "C" void kernel_launch(void* const* d_in, const int* in_sizes, int n_in,
                              void* d_out, int out_size, void* d_ws,
                              size_t ws_size, hipStream_t stream) {
  const float* X = (const float*)d_in[0];
  const float* W1 = (const float*)d_in[1];
  const float* W2 = (const float*)d_in[2];
  const float* W3 = (const float*)d_in[3];
  const float* W4 = (const float*)d_in[4];
  float* out = (float*)d_out;

  char* ws = (char*)d_ws;
  unsigned int* cnt = (unsigned int*)ws;             // 256 B
  float* Z = (float*)(ws + 256);                     // 65,536,000
  uint8_t* Sa = (uint8_t*)(ws + 256 + 65536000ull);  // 16,384,000
  uint8_t* Sb = Sa + 16384000ull;                    // 16,384,000
  uint8_t* Sin = Sb + 16384000ull;                   // 2,048,000
  float* Wt1 = (float*)(Sin + 2048000ull);           // 32*256*4
  float* Wt2 = Wt1 + 32 * 256;                       // 256*256*4
  float* Wt3 = Wt2 + 256 * 256;                      // 256*256*4
  float* Wt4 = Wt3 + 256 * 256;                      // 256*128*4

  hipMemsetAsync(cnt, 0, 16, stream);
  prep_w<<<(32 * 256 + 255) / 256, 256, 0, stream>>>(W1, Wt1, 256, 20, 32, 256);
  prep_w<<<(256 * 256) / 256, 256, 0, stream>>>(W2, Wt2, 256, 256, 256, 256);
  prep_w<<<(256 * 256) / 256, 256, 0, stream>>>(W3, Wt3, 256, 256, 256, 256);
  prep_w<<<(256 * 128) / 256, 256, 0, stream>>>(W4, Wt4, 35, 256, 256, 128);
  prep_input<<<(NB + 255) / 256, 256, 0, stream>>>(X, Sin);

  dim3 gBig(500, 2);  // 128-row tiles, O=256
  dim3 gOut(500, 1);  // layer 4 (O=35 padded to 128)

  gemm_u8<<<gBig, 256, 0, stream>>>(Sin, Wt1, Z, 32, 256, 256, 256);
  cuba_kernel<false><<<256, 64, 0, stream>>>(Z, Sa, nullptr, cnt + 0, 256,
                                             16384);
  gemm_u8<<<gBig, 256, 0, stream>>>(Sa, Wt2, Z, 256, 256, 256, 256);
  cuba_kernel<false><<<256, 64, 0, stream>>>(Z, Sb, nullptr, cnt + 1, 256,
                                             16384);
  gemm_u8<<<gBig, 256, 0, stream>>>(Sb, Wt3, Z, 256, 256, 256, 256);
  cuba_kernel<false><<<256, 64, 0, stream>>>(Z, Sa, nullptr, cnt + 2, 256,
                                             16384);
  gemm_u8<<<gOut, 256, 0, stream>>>(Sa, Wt4, Z, 256, 128, 35, 35);
  cuba_kernel<true><<<35, 64, 0, stream>>>(Z, nullptr, out, cnt + 3, 35, 2240);
  finalize_counts<<<1, 64, 0, stream>>>(cnt, out + 2240000);
}

// Round 9
// 497.155 us; speedup vs baseline: 11.4882x; 1.0113x over previous
//
#include <hip/hip_runtime.h>
#include <cstdint>
#include <cstddef>

#define TT 1000
#define NB 64000  // B*T

// ---------------------------------------------------------------------------
// NUMERICS CONTRACT (r1/r5/r6/r8 verified absmax 0.0): each z[n,o] is ONE
// ascending-k fp32 fmaf chain. Do not reorder, split, or tree-reduce.
// ---------------------------------------------------------------------------

// async global->LDS DMA: 16B/lane; LDS dest = wave-uniform base + lane*16
__device__ __forceinline__ void dma16(const void* g, void* l) {
  __builtin_amdgcn_global_load_lds(
      (const __attribute__((address_space(1))) unsigned int*)g,
      (__attribute__((address_space(3))) unsigned int*)l, 16, 0, 0);
}

// ---------------------------------------------------------------------------
// Spike layout (DMA-image): Aswz[nblk][kt][d][r] u32, nblk=n>>7, r=n&127,
// k = kt*16 + d*4 + byte. One k-tile = 512 dwords = 2048 B contiguous.
// ---------------------------------------------------------------------------

// ---------------------------------------------------------------------------
// gemm_dma: Z[n,o] = sum_k Wt[k][o] * S[n][k]
// 128n x 128o tile, BK=16, 256 thr, 8x8/thread. Double-buffered LDS, ONE
// barrier per k-tile; ALL staging via zero-VGPR global_load_lds (A packed
// u8 dwords + B f32 rows), issued a full compute-tile ahead -> latency
// hidden, barrier drain ~free. A bytes -> v_cvt_f32_ubyte in compute.
// ---------------------------------------------------------------------------
__global__ __launch_bounds__(256) void gemm_dma(
    const unsigned int* __restrict__ Aswz, const float* __restrict__ Wt,
    float* __restrict__ Z, int KT, int Wld, int Zld, int Ostore) {
  __shared__ unsigned int AsU[2][512];       // [buf][kq*128 + row]
  __shared__ __align__(16) float Bs[2][2048];  // [buf][k*128 + o]
  const int t = threadIdx.x;
  const int lane = t & 63;
  const int wave = t >> 6;
  const int bn = blockIdx.x * 128;
  const int bo = blockIdx.y * 128;
  const int tx4 = (t & 15) * 4;
  const int ty4 = ((t >> 4) & 15) * 4;

  // B DMA geometry: flat 2048-float tile; wave covers 2x 1KB segments
  const int f0 = wave * 64 + lane;  // 0..255, lane covers floats f0*4..+3
  const int bk0 = f0 >> 5;          // k-row 0..7 (second dma: +8)
  const int bc0 = (f0 & 31) * 4;
  const float* wsrc = Wt + (size_t)bk0 * Wld + bo + bc0;
  // A DMA: waves 0,1 cover 512 dwords (2048 B) per tile
  const unsigned int* asrc =
      Aswz + (size_t)blockIdx.x * KT * 512 + wave * 256 + lane * 4;

  float acc[8][8];
#pragma unroll
  for (int j = 0; j < 8; j++)
#pragma unroll
    for (int i = 0; i < 8; i++) acc[j][i] = 0.f;

  // prologue: stage tile 0
  dma16(wsrc, &Bs[0][wave * 256]);
  dma16(wsrc + (size_t)8 * Wld, &Bs[0][1024 + wave * 256]);
  if (wave < 2) dma16(asrc, &AsU[0][wave * 256]);
  __syncthreads();

  for (int tile = 0; tile < KT; tile++) {
    const int cur = tile & 1, nxt = cur ^ 1;
    if (tile + 1 < KT) {  // async staging for next tile (zero VGPR cost)
      const float* wn = wsrc + (size_t)(tile + 1) * 16 * Wld;
      dma16(wn, &Bs[nxt][wave * 256]);
      dma16(wn + (size_t)8 * Wld, &Bs[nxt][1024 + wave * 256]);
      if (wave < 2) dma16(asrc + (size_t)(tile + 1) * 512, &AsU[nxt][wave * 256]);
    }
#pragma unroll
    for (int kq = 0; kq < 4; kq++) {
      uint4 a0 = *(const uint4*)&AsU[cur][kq * 128 + ty4];
      uint4 a1 = *(const uint4*)&AsU[cur][kq * 128 + 64 + ty4];
#pragma unroll
      for (int k2 = 0; k2 < 4; k2++) {
        const int kk = kq * 4 + k2;
        const int sh = k2 * 8;
        float av[8];
        av[0] = (float)((a0.x >> sh) & 0xffu);  // v_cvt_f32_ubyte
        av[1] = (float)((a0.y >> sh) & 0xffu);
        av[2] = (float)((a0.z >> sh) & 0xffu);
        av[3] = (float)((a0.w >> sh) & 0xffu);
        av[4] = (float)((a1.x >> sh) & 0xffu);
        av[5] = (float)((a1.y >> sh) & 0xffu);
        av[6] = (float)((a1.z >> sh) & 0xffu);
        av[7] = (float)((a1.w >> sh) & 0xffu);
        float4 b0 = *(const float4*)&Bs[cur][kk * 128 + tx4];
        float4 b1 = *(const float4*)&Bs[cur][kk * 128 + 64 + tx4];
        float bv[8] = {b0.x, b0.y, b0.z, b0.w, b1.x, b1.y, b1.z, b1.w};
#pragma unroll
        for (int j = 0; j < 8; j++)
#pragma unroll
          for (int i = 0; i < 8; i++)
            acc[j][i] = fmaf(av[j], bv[i], acc[j][i]);
      }
    }
    __syncthreads();  // drains next-tile DMAs (landed during compute)
  }

  // store (N multiple of 128; o guarded vs Ostore)
#pragma unroll
  for (int jp = 0; jp < 2; jp++) {
#pragma unroll
    for (int j = 0; j < 4; j++) {
      int n = bn + jp * 64 + ty4 + j;
#pragma unroll
      for (int ip = 0; ip < 2; ip++) {
        int o0 = bo + ip * 64 + tx4;
        const float* a = &acc[jp * 4 + j][ip * 4];
        float* zp = Z + (size_t)n * Zld + o0;
        if (o0 + 3 < Ostore) {
          *(float4*)zp = make_float4(a[0], a[1], a[2], a[3]);
        } else {
#pragma unroll
          for (int q = 0; q < 4; q++)
            if (o0 + q < Ostore) zp[q] = a[q];
        }
      }
    }
  }
}

// ---------------------------------------------------------------------------
// CUBA LIF recurrence: depth-4 x U=25 load pipeline. Exact per-step fp32
// mul/add chain. Mid layers write u8 spikes into the DMA-image layout
// (KT=16): byte addr = (n>>7)*32768 + koff + (n&127)*4.
// ---------------------------------------------------------------------------
template <bool FINAL>
__global__ __launch_bounds__(64) void cuba_kernel(
    const float* __restrict__ Z, uint8_t* __restrict__ Sout,
    float* __restrict__ Fout, unsigned int* __restrict__ cnt, int O,
    int total) {
  int gid = blockIdx.x * 64 + threadIdx.x;
  unsigned int c = 0;
  if (gid < total) {
    int b = gid / O;
    int o = gid - b * O;
    const int nb = b * TT;
    const float* zp = Z + (size_t)nb * O + o;
    float* fp = Fout + ((size_t)b * O + o) * TT;
    const int koff = (o >> 4) * 2048 + ((o >> 2) & 3) * 512 + (o & 3);
    float cur = 0.f, volt = 0.f;
    constexpr int U = 25;
    float z0[U], z1[U], z2[U], z3[U];

#define LOADB(buf, tbase)                         \
  _Pragma("unroll") for (int u = 0; u < U; u++) { \
    buf[u] = zp[(size_t)((tbase) + u) * O];       \
  }
#define COMPB(buf, tbase)                                              \
  _Pragma("unroll") for (int u = 0; u < U; u++) {                      \
    cur = __fadd_rn(__fmul_rn(0.75f, cur), buf[u]);                    \
    volt = __fadd_rn(__fmul_rn(0.97f, volt), cur);                     \
    bool fire = volt >= 1.25f;                                         \
    volt = fire ? 0.f : volt;                                          \
    c += fire ? 1u : 0u;                                               \
    if (FINAL) {                                                       \
      fp[(tbase) + u] = fire ? 1.f : 0.f;                              \
    } else {                                                           \
      int n = nb + (tbase) + u;                                        \
      Sout[(size_t)(n >> 7) * 32768 + koff + ((n & 127) << 2)] =       \
          (uint8_t)(fire ? 1 : 0);                                     \
    }                                                                  \
  }

    LOADB(z0, 0)
    LOADB(z1, U)
    LOADB(z2, 2 * U)
    for (int i = 0; i < 10; i++) {
      const int base = i * 4 * U;
      LOADB(z3, base + 3 * U)
      COMPB(z0, base)
      if (i < 9) LOADB(z0, base + 4 * U)
      COMPB(z1, base + U)
      if (i < 9) LOADB(z1, base + 5 * U)
      COMPB(z2, base + 2 * U)
      if (i < 9) LOADB(z2, base + 6 * U)
      COMPB(z3, base + 3 * U)
    }
#undef LOADB
#undef COMPB
  }
#pragma unroll
  for (int off = 32; off; off >>= 1) c += __shfl_down(c, off, 64);
  if ((threadIdx.x & 63) == 0) atomicAdd(cnt, c);
}

// ---------------------------------------------------------------------------
// Fused prep: cnt zero + input swizzle (KT=2 image) + 4 weight transposes.
// Block ranges: [0,250) input; [250,282) W1; [282,538) W2; [538,794) W3;
// [794,922) W4.
// ---------------------------------------------------------------------------
__device__ __forceinline__ void prep_w_item(const float* __restrict__ W,
                                            float* __restrict__ Wt, int O,
                                            int K, int Opad, int i) {
  int k = i / Opad, o = i - k * Opad;
  Wt[i] = (k < K && o < O) ? W[(size_t)o * K + k] : 0.f;
}

__global__ __launch_bounds__(256) void prep_all(
    const float* __restrict__ X, const float* __restrict__ W1,
    const float* __restrict__ W2, const float* __restrict__ W3,
    const float* __restrict__ W4, unsigned int* __restrict__ Ain,
    float* __restrict__ Wt1, float* __restrict__ Wt2,
    float* __restrict__ Wt3, float* __restrict__ Wt4,
    unsigned int* __restrict__ cnt) {
  const int blk = blockIdx.x;
  const int tid = threadIdx.x;
  if (blk == 0 && tid < 8) cnt[tid] = 0u;
  if (blk < 250) {
    int gid = blk * 256 + tid;  // n
    unsigned int w[8];
#pragma unroll
    for (int i = 0; i < 8; i++) w[i] = 0u;
#pragma unroll
    for (int c = 0; c < 20; c++) {
      float v = X[((size_t)(gid / TT) * 20 + c) * TT + (gid % TT)];
      w[c >> 2] |= (v != 0.f ? 1u : 0u) << ((c & 3) * 8);
    }
    unsigned int base = (gid >> 7) * 1024 + (gid & 127);
#pragma unroll
    for (int kd = 0; kd < 8; kd++)
      Ain[base + (kd >> 2) * 512 + (kd & 3) * 128] = w[kd];
  } else if (blk < 282) {
    prep_w_item(W1, Wt1, 256, 20, 256, (blk - 250) * 256 + tid);
  } else if (blk < 538) {
    prep_w_item(W2, Wt2, 256, 256, 256, (blk - 282) * 256 + tid);
  } else if (blk < 794) {
    prep_w_item(W3, Wt3, 256, 256, 256, (blk - 538) * 256 + tid);
  } else {
    prep_w_item(W4, Wt4, 35, 256, 128, (blk - 794) * 256 + tid);
  }
}

__global__ void finalize_counts(const unsigned int* __restrict__ cnt,
                                float* __restrict__ out) {
  int i = threadIdx.x;
  if (i < 4) {
    const float denom[4] = {16384000.f, 16384000.f, 16384000.f, 2240000.f};
    out[i] = (float)cnt[i] / denom[i];
  }
}

// ---------------------------------------------------------------------------
extern "C" void kernel_launch(void* const* d_in, const int* in_sizes, int n_in,
                              void* d_out, int out_size, void* d_ws,
                              size_t ws_size, hipStream_t stream) {
  const float* X = (const float*)d_in[0];
  const float* W1 = (const float*)d_in[1];
  const float* W2 = (const float*)d_in[2];
  const float* W3 = (const float*)d_in[3];
  const float* W4 = (const float*)d_in[4];
  float* out = (float*)d_out;

  char* ws = (char*)d_ws;
  unsigned int* cnt = (unsigned int*)ws;              // 256 B
  float* Z = (float*)(ws + 256);                      // 65,536,000
  unsigned int* Sa = (unsigned int*)(ws + 256 + 65536000ull);  // 16,384,000
  unsigned int* Sb = Sa + 4096000ull;                 // 16,384,000
  unsigned int* Sin = Sb + 4096000ull;                // 2,048,000
  float* Wt1 = (float*)(Sin + 512000ull);             // 32*256*4
  float* Wt2 = Wt1 + 32 * 256;                        // 256*256*4
  float* Wt3 = Wt2 + 256 * 256;                       // 256*256*4
  float* Wt4 = Wt3 + 256 * 256;                       // 256*128*4

  prep_all<<<922, 256, 0, stream>>>(X, W1, W2, W3, W4, Sin, Wt1, Wt2, Wt3,
                                    Wt4, cnt);

  dim3 gBig(500, 2);
  dim3 gOut(500, 1);

  gemm_dma<<<gBig, 256, 0, stream>>>(Sin, Wt1, Z, 2, 256, 256, 256);
  cuba_kernel<false><<<256, 64, 0, stream>>>(Z, (uint8_t*)Sa, nullptr, cnt + 0,
                                             256, 16384);
  gemm_dma<<<gBig, 256, 0, stream>>>(Sa, Wt2, Z, 16, 256, 256, 256);
  cuba_kernel<false><<<256, 64, 0, stream>>>(Z, (uint8_t*)Sb, nullptr, cnt + 1,
                                             256, 16384);
  gemm_dma<<<gBig, 256, 0, stream>>>(Sb, Wt3, Z, 16, 256, 256, 256);
  cuba_kernel<false><<<256, 64, 0, stream>>>(Z, (uint8_t*)Sa, nullptr, cnt + 2,
                                             256, 16384);
  gemm_dma<<<gOut, 256, 0, stream>>>(Sa, Wt4, Z, 16, 128, 35, 35);
  cuba_kernel<true><<<35, 64, 0, stream>>>(Z, nullptr, out, cnt + 3, 35, 2240);
  finalize_counts<<<1, 64, 0, stream>>>(cnt, out + 2240000);
}